// Round 6
// baseline (227.670 us; speedup 1.0000x reference)
//
#include <hip/hip_runtime.h>
#include <math.h>

#define BATCH 4
#define NN    12288
#define CIN   3
#define NC    4096
#define NG    12
#define NB    256
#define HSTR  9            // LDS hist layout [d][bucket][ch], stride 9 (bank spread)
#define TPB   512

// One kernel does everything. Block = (group g, chunk of 256 nodes).
// Each block redundantly computes its group's scale + full bucket histogram
// in LDS (data is L2-hot across the 16 blocks of a group), scans it, then
// applies coupling + gamma + normalize for its own 256 nodes.
__launch_bounds__(TPB)
__global__ void k_fused(const float* __restrict__ spikes,
                        const float* __restrict__ theta,
                        const float* __restrict__ gamma,
                        float* __restrict__ out) {
    __shared__ float lh[4 * NB * HSTR];          // 36 KB
    __shared__ float redmn[8], redmx[8];
    __shared__ float uScale, uAmin;

    int blk = blockIdx.x;
    int g = blk >> 4, chunk = blk & 15;
    int b = g / CIN, c = g % CIN;
    int tid = threadIdx.x, lane = tid & 63, w = tid >> 6;

    // zero histogram (4*256*9 = 9216 floats)
    #pragma unroll
    for (int q = 0; q < 18; ++q) lh[tid + q * TPB] = 0.f;

    // ---- phase 1: group min/max of channel c (full row, coalesced float4) ----
    const float4* srow = (const float4*)(spikes + b * NN);
    float mn = 1e30f, mx = -1e30f;
    #pragma unroll
    for (int q = 0; q < 6; ++q) {
        int f = tid + q * TPB;                   // float4 index 0..3071
        float4 v4 = srow[f];
        int fr = f % 3;
        int m = (c - fr + 3) % 3;                // element j with (f+j)%3 == c
        float e0 = (m == 0) ? v4.x : ((m == 1) ? v4.y : v4.z);
        mn = fminf(mn, e0); mx = fmaxf(mx, e0);
        if (m == 0) { mn = fminf(mn, v4.w); mx = fmaxf(mx, v4.w); }
    }
    #pragma unroll
    for (int off = 32; off; off >>= 1) {
        mn = fminf(mn, __shfl_down(mn, off));
        mx = fmaxf(mx, __shfl_down(mx, off));
    }
    if (lane == 0) { redmn[w] = mn; redmx[w] = mx; }
    __syncthreads();                              // covers lh zero too
    if (tid == 0) {
        float m0 = redmn[0], m1 = redmx[0];
        #pragma unroll
        for (int i = 1; i < 8; ++i) { m0 = fminf(m0, redmn[i]); m1 = fmaxf(m1, redmx[i]); }
        float scale = 0.25f / fmaxf(m1 - m0, 1e-6f);
        uScale = scale;
        uAmin  = m0 * scale;
    }
    __syncthreads();
    float scale = uScale, amin = uAmin;

    // ---- phase 2: full-group histogram (8 elems/thread, 4 dims, 8 channels) ----
    #pragma unroll
    for (int q = 0; q < 8; ++q) {
        int k = tid + q * TPB;                   // element in group, 0..4095
        int v = b * NN + k * CIN + c;
        float a = spikes[v] * scale;
        int bb = (int)((a - amin) * (4.0f * NB));
        bb = bb < 0 ? 0 : (bb > NB - 1 ? NB - 1 : bb);
        float sa, ca; __sincosf(a, &sa, &ca);
        float4 th = ((const float4*)theta)[v];
        float thv[4] = {th.x, th.y, th.z, th.w};
        #pragma unroll
        for (int d = 0; d < 4; ++d) {
            float sth, cth; __sincosf(thv[d], &sth, &cth);
            float sf = fmaf(cth, sa,  sth * ca); // sin(th + a)
            float cf = fmaf(-sth, sa, cth * ca); // cos(th + a)
            float sp = fmaf(-cth, sa, sth * ca); // sin(th - a)
            float cq = fmaf(sth, sa,  cth * ca); // cos(th - a)
            float* h = lh + (d * NB + bb) * HSTR;
            atomicAdd(h + 0, sf);      atomicAdd(h + 1, cf);
            atomicAdd(h + 2, a * sf);  atomicAdd(h + 3, a * cf);
            atomicAdd(h + 4, sp);      atomicAdd(h + 5, cq);
            atomicAdd(h + 6, a * sp);  atomicAdd(h + 7, a * cq);
        }
    }
    __syncthreads();

    // ---- phase 3: inclusive prefix scan over buckets, per (d,ch) ----
    #pragma unroll
    for (int p = 0; p < 4; ++p) {
        int pair = w * 4 + p;                    // 0..31
        int d = pair >> 3, ch = pair & 7;
        float* H = lh + d * NB * HSTR + ch;
        float x0 = H[(lane * 4 + 0) * HSTR];
        float x1 = H[(lane * 4 + 1) * HSTR];
        float x2 = H[(lane * 4 + 2) * HSTR];
        float x3 = H[(lane * 4 + 3) * HSTR];
        float i0 = x0, i1 = i0 + x1, i2 = i1 + x2, i3 = i2 + x3;
        float incl = i3;
        #pragma unroll
        for (int off = 1; off < 64; off <<= 1) {
            float o = __shfl_up(incl, off);
            if (lane >= off) incl += o;
        }
        float ebt = incl - i3;
        H[(lane * 4 + 0) * HSTR] = ebt + i0;
        H[(lane * 4 + 1) * HSTR] = ebt + i1;
        H[(lane * 4 + 2) * HSTR] = ebt + i2;
        H[(lane * 4 + 3) * HSTR] = ebt + i3;
    }
    __syncthreads();

    // ---- phase 4: apply for this block's 256 nodes ----
    if (tid < 256) {
        int k = chunk * 256 + tid;
        int v = b * NN + k * CIN + c;
        float a = spikes[v] * scale;
        int bb = (int)((a - amin) * (4.0f * NB));
        bb = bb < 0 ? 0 : (bb > NB - 1 ? NB - 1 : bb);
        float sa, ca; __sincosf(a, &sa, &ca);
        float4 th = ((const float4*)theta)[v];
        float4 gm = ((const float4*)gamma)[v];
        float thv[4] = {th.x, th.y, th.z, th.w};
        float cp[4];
        #pragma unroll
        for (int d = 0; d < 4; ++d) {
            float sth, cth; __sincosf(thv[d], &sth, &cth);
            float sf = fmaf(cth, sa,  sth * ca);
            float cf = fmaf(-sth, sa, cth * ca);
            float sp = fmaf(-cth, sa, sth * ca);
            float cq = fmaf(sth, sa,  cth * ca);
            const float* H = lh + d * NB * HSTR;
            const float* Pb = H + bb * HSTR;
            float P0 = Pb[0], P1 = Pb[1], P2 = Pb[2], P3 = Pb[3];
            float P4 = Pb[4], P5 = Pb[5], P6 = Pb[6], P7 = Pb[7];
            const float* Tt = H + (NB - 1) * HSTR;
            float S4 = Tt[4] - P4, S5 = Tt[5] - P5;
            float S6 = Tt[6] - P6, S7 = Tt[7] - P7;
            float lowS = fmaf(0.25f - a, P0, P2);
            float lowC = fmaf(0.25f - a, P1, P3);
            float lower = cf * lowS - sf * lowC;
            float upS = fmaf(0.25f + a, S4, -S6);
            float upC = fmaf(0.25f + a, S5, -S7);
            float upper = cq * upS - sp * upC;
            cp[d] = (lower + upper) * (1.0f / (float)NC);
        }
        float tx = gm.x + cp[0], ty = gm.y + cp[1];
        float tz = gm.z + cp[2], tw = gm.w + cp[3];
        float nrm = sqrtf(tx * tx + ty * ty + tz * tz + tw * tw);
        float inv = 1.0f / fmaxf(nrm, 1e-6f);
        ((float4*)out)[v] = make_float4(tx * inv, ty * inv, tz * inv, tw * inv);
    }
}

extern "C" void kernel_launch(void* const* d_in, const int* in_sizes, int n_in,
                              void* d_out, int out_size, void* d_ws, size_t ws_size,
                              hipStream_t stream) {
    const float* theta  = (const float*)d_in[0];
    const float* gamma  = (const float*)d_in[1];
    const float* spikes = (const float*)d_in[2];
    float* out = (float*)d_out;
    (void)d_ws; (void)ws_size;

    hipLaunchKernelGGL(k_fused, dim3(NG * 16), dim3(TPB), 0, stream,
                       spikes, theta, gamma, out);
}

// Round 7
// 92.451 us; speedup vs baseline: 2.4626x; 2.4626x over previous
//
#include <hip/hip_runtime.h>
#include <math.h>

#define BATCH 4
#define NN    12288
#define CIN   3
#define NC    4096
#define NG    12
#define NB    256
#define HSTR  9                 // LDS hist stride: [d][bucket][ch], 9 floats
#define HS    (4 * NB * 8)      // dense partial size per block = 8192 floats

// ws float-offsets
#define SC_OFF   0              // per group: scale, amin  [NG*2]
#define PART_OFF 64             // partials [192][HS] = 1.57M floats (6 MB)

// ---------- kernel 1: per (group,chunk): stats + own-chunk partial hist ----
__launch_bounds__(256)
__global__ void k_part(const float* __restrict__ spikes,
                       const float* __restrict__ theta,
                       float* __restrict__ ws) {
    __shared__ float lh[4 * NB * HSTR];           // 36 KB
    __shared__ float redmn[4], redmx[4];
    __shared__ float uScale, uAmin;

    int blk = blockIdx.x;
    int g = blk >> 4, chunk = blk & 15;
    int b = g / CIN, c = g % CIN;
    int tid = threadIdx.x, lane = tid & 63, w = tid >> 6;

    // zero hist (4*256*9 = 9216 floats)
    #pragma unroll
    for (int q = 0; q < 36; ++q) lh[tid + q * 256] = 0.f;

    // group min/max (redundant per block; row is L2-hot), keep own element
    float sown = 0.f, mn = 1e30f, mx = -1e30f;
    #pragma unroll
    for (int q = 0; q < 16; ++q) {
        float s = spikes[b * NN + (tid + q * 256) * CIN + c];
        if (q == chunk) sown = s;
        mn = fminf(mn, s); mx = fmaxf(mx, s);
    }
    #pragma unroll
    for (int off = 32; off; off >>= 1) {
        mn = fminf(mn, __shfl_down(mn, off));
        mx = fmaxf(mx, __shfl_down(mx, off));
    }
    if (lane == 0) { redmn[w] = mn; redmx[w] = mx; }
    __syncthreads();                               // also covers lh zeroing
    if (tid == 0) {
        float m0 = fminf(fminf(redmn[0], redmn[1]), fminf(redmn[2], redmn[3]));
        float m1 = fmaxf(fmaxf(redmx[0], redmx[1]), fmaxf(redmx[2], redmx[3]));
        float scale = 0.25f / fmaxf(m1 - m0, 1e-6f);
        uScale = scale;
        uAmin  = m0 * scale;
    }
    __syncthreads();
    float scale = uScale, amin = uAmin;

    // own element -> 4 dims x 8 channels into LDS hist
    int k = chunk * 256 + tid;
    int v = b * NN + k * CIN + c;
    float a = sown * scale;
    int bb = (int)((a - amin) * (4.0f * NB));
    bb = bb < 0 ? 0 : (bb > NB - 1 ? NB - 1 : bb);
    float sa, ca; __sincosf(a, &sa, &ca);
    float4 th = ((const float4*)theta)[v];
    float thv[4] = {th.x, th.y, th.z, th.w};
    #pragma unroll
    for (int d = 0; d < 4; ++d) {
        float sth, cth; __sincosf(thv[d], &sth, &cth);
        float sf = fmaf(cth, sa,  sth * ca);       // sin(th + a)
        float cf = fmaf(-sth, sa, cth * ca);       // cos(th + a)
        float sp = fmaf(-cth, sa, sth * ca);       // sin(th - a)
        float cq = fmaf(sth, sa,  cth * ca);       // cos(th - a)
        float* h = lh + (d * NB + bb) * HSTR;
        atomicAdd(h + 0, sf);      atomicAdd(h + 1, cf);
        atomicAdd(h + 2, a * sf);  atomicAdd(h + 3, a * cf);
        atomicAdd(h + 4, sp);      atomicAdd(h + 5, cq);
        atomicAdd(h + 6, a * sp);  atomicAdd(h + 7, a * cq);
    }
    __syncthreads();

    // write dense partial (coalesced), plus per-group scale once
    float* P = ws + PART_OFF + (size_t)blk * HS;
    #pragma unroll
    for (int q = 0; q < 32; ++q) {
        int o = tid + q * 256;                     // (d*NB+b)*8 + ch
        P[o] = lh[(o >> 3) * HSTR + (o & 7)];
    }
    if (chunk == 0 && tid == 0) {
        ws[SC_OFF + g * 2]     = scale;
        ws[SC_OFF + g * 2 + 1] = amin;
    }
}

// ---------- kernel 2: merge 16 partials + scan + apply + normalize ---------
__launch_bounds__(256)
__global__ void k_apply(const float* __restrict__ spikes,
                        const float* __restrict__ theta,
                        const float* __restrict__ gamma,
                        const float* __restrict__ ws,
                        float* __restrict__ out) {
    __shared__ float lh[4 * NB * HSTR];            // 36 KB
    int blk = blockIdx.x;
    int g = blk >> 4, chunk = blk & 15;
    int b = g / CIN, c = g % CIN;
    int tid = threadIdx.x, lane = tid & 63, w = tid >> 6;

    // sum the group's 16 partials (coalesced float4), store to LDS layout
    const float4* Pg = (const float4*)(ws + PART_OFF + (size_t)(g * 16) * HS);
    #pragma unroll
    for (int q = 0; q < 8; ++q) {
        int o4 = tid + q * 256;                    // float4 slot, < HS/4
        float4 s = make_float4(0.f, 0.f, 0.f, 0.f);
        #pragma unroll
        for (int p = 0; p < 16; ++p) {
            float4 x = Pg[p * (HS / 4) + o4];
            s.x += x.x; s.y += x.y; s.z += x.z; s.w += x.w;
        }
        int o = o4 * 4;
        lh[((o + 0) >> 3) * HSTR + ((o + 0) & 7)] = s.x;
        lh[((o + 1) >> 3) * HSTR + ((o + 1) & 7)] = s.y;
        lh[((o + 2) >> 3) * HSTR + ((o + 2) & 7)] = s.z;
        lh[((o + 3) >> 3) * HSTR + ((o + 3) & 7)] = s.w;
    }
    __syncthreads();

    // inclusive prefix scan over buckets; 4 waves x 8 (d,ch) pairs
    #pragma unroll
    for (int p = 0; p < 8; ++p) {
        int pair = w * 8 + p;                      // 0..31
        int d = pair >> 3, ch = pair & 7;
        float* H = lh + d * NB * HSTR + ch;
        float x0 = H[(lane * 4 + 0) * HSTR];
        float x1 = H[(lane * 4 + 1) * HSTR];
        float x2 = H[(lane * 4 + 2) * HSTR];
        float x3 = H[(lane * 4 + 3) * HSTR];
        float i0 = x0, i1 = i0 + x1, i2 = i1 + x2, i3 = i2 + x3;
        float incl = i3;
        #pragma unroll
        for (int off = 1; off < 64; off <<= 1) {
            float o = __shfl_up(incl, off);
            if (lane >= off) incl += o;
        }
        float ebt = incl - i3;
        H[(lane * 4 + 0) * HSTR] = ebt + i0;
        H[(lane * 4 + 1) * HSTR] = ebt + i1;
        H[(lane * 4 + 2) * HSTR] = ebt + i2;
        H[(lane * 4 + 3) * HSTR] = ebt + i3;
    }
    __syncthreads();

    // apply for this block's 256 nodes + gamma + normalize
    float scale = ws[SC_OFF + g * 2], amin = ws[SC_OFF + g * 2 + 1];
    int k = chunk * 256 + tid;
    int v = b * NN + k * CIN + c;
    float a = spikes[v] * scale;
    int bb = (int)((a - amin) * (4.0f * NB));
    bb = bb < 0 ? 0 : (bb > NB - 1 ? NB - 1 : bb);
    float sa, ca; __sincosf(a, &sa, &ca);
    float4 th = ((const float4*)theta)[v];
    float4 gm = ((const float4*)gamma)[v];
    float thv[4] = {th.x, th.y, th.z, th.w};
    float cp[4];
    #pragma unroll
    for (int d = 0; d < 4; ++d) {
        float sth, cth; __sincosf(thv[d], &sth, &cth);
        float sf = fmaf(cth, sa,  sth * ca);
        float cf = fmaf(-sth, sa, cth * ca);
        float sp = fmaf(-cth, sa, sth * ca);
        float cq = fmaf(sth, sa,  cth * ca);
        const float* H  = lh + d * NB * HSTR;
        const float* Pb = H + bb * HSTR;
        const float* Tt = H + (NB - 1) * HSTR;
        float P0 = Pb[0], P1 = Pb[1], P2 = Pb[2], P3 = Pb[3];
        float S4 = Tt[4] - Pb[4], S5 = Tt[5] - Pb[5];
        float S6 = Tt[6] - Pb[6], S7 = Tt[7] - Pb[7];
        float lowS = fmaf(0.25f - a, P0, P2);
        float lowC = fmaf(0.25f - a, P1, P3);
        float lower = cf * lowS - sf * lowC;
        float upS = fmaf(0.25f + a, S4, -S6);
        float upC = fmaf(0.25f + a, S5, -S7);
        float upper = cq * upS - sp * upC;
        cp[d] = (lower + upper) * (1.0f / (float)NC);
    }
    float tx = gm.x + cp[0], ty = gm.y + cp[1];
    float tz = gm.z + cp[2], tw = gm.w + cp[3];
    float nrm = sqrtf(tx * tx + ty * ty + tz * tz + tw * tw);
    float inv = 1.0f / fmaxf(nrm, 1e-6f);
    ((float4*)out)[v] = make_float4(tx * inv, ty * inv, tz * inv, tw * inv);
}

extern "C" void kernel_launch(void* const* d_in, const int* in_sizes, int n_in,
                              void* d_out, int out_size, void* d_ws, size_t ws_size,
                              hipStream_t stream) {
    const float* theta  = (const float*)d_in[0];
    const float* gamma  = (const float*)d_in[1];
    const float* spikes = (const float*)d_in[2];
    float* out = (float*)d_out;
    float* ws  = (float*)d_ws;

    hipLaunchKernelGGL(k_part,  dim3(NG * 16), dim3(256), 0, stream, spikes, theta, ws);
    hipLaunchKernelGGL(k_apply, dim3(NG * 16), dim3(256), 0, stream,
                       spikes, theta, gamma, ws, out);
}

// Round 8
// 80.031 us; speedup vs baseline: 2.8448x; 1.1552x over previous
//
#include <hip/hip_runtime.h>
#include <math.h>

#define BATCH 4
#define NN    12288
#define CIN   3
#define NC    4096
#define NG    12
#define NB    128
#define HSTR  9                  // LDS hist stride: [d][bucket][ch] x 9 floats
#define PSZ   (4 * NB * 8)       // dense partial per hist-block = 4096 floats

// ws float-offsets
#define SC_OFF 0                             // per group: scale, amin [NG*2]
#define P_OFF  64                            // partials [192][PSZ] = 786432 floats
#define H2_OFF (P_OFF + 192 * PSZ)           // scanned hist [NG*4][NB*8] = 49152 floats

// ---------- kernel 1: per-group min/max -> scale, amin ---------------------
__launch_bounds__(256)
__global__ void k_stats(const float* __restrict__ spikes, float* __restrict__ ws) {
    int g = blockIdx.x, b = g / CIN, c = g % CIN;
    const float4* row = (const float4*)(spikes + b * NN);
    int tid = threadIdx.x, lane = tid & 63, w = tid >> 6;
    float mn = 1e30f, mx = -1e30f;
    #pragma unroll
    for (int q = 0; q < 12; ++q) {
        int f = tid + q * 256;               // float4 index, < 3072
        float4 v4 = row[f];
        float e[4] = {v4.x, v4.y, v4.z, v4.w};
        int r = (4 * f) % 3;                 // channel of element j=0
        int j0 = (c - r + 3) % 3;            // first j with channel c
        mn = fminf(mn, e[j0]); mx = fmaxf(mx, e[j0]);
        if (j0 + 3 < 4) { mn = fminf(mn, e[j0 + 3]); mx = fmaxf(mx, e[j0 + 3]); }
    }
    #pragma unroll
    for (int off = 32; off; off >>= 1) {
        mn = fminf(mn, __shfl_down(mn, off));
        mx = fmaxf(mx, __shfl_down(mx, off));
    }
    __shared__ float smn[4], smx[4];
    if (lane == 0) { smn[w] = mn; smx[w] = mx; }
    __syncthreads();
    if (tid == 0) {
        float m0 = fminf(fminf(smn[0], smn[1]), fminf(smn[2], smn[3]));
        float m1 = fmaxf(fmaxf(smx[0], smx[1]), fmaxf(smx[2], smx[3]));
        float scale = 0.25f / fmaxf(m1 - m0, 1e-6f);
        ws[SC_OFF + g * 2]     = scale;
        ws[SC_OFF + g * 2 + 1] = m0 * scale;
    }
}

// ---------- kernel 2: per (group,chunk): own-chunk LDS hist -> dense partial
__launch_bounds__(256)
__global__ void k_hist(const float* __restrict__ spikes,
                       const float* __restrict__ theta,
                       float* __restrict__ ws) {
    __shared__ float lh[4 * NB * HSTR];       // 4608 floats = 18 KB
    int blk = blockIdx.x, g = blk >> 4, chunk = blk & 15;
    int b = g / CIN, c = g % CIN;
    int tid = threadIdx.x;
    #pragma unroll
    for (int q = 0; q < 18; ++q) lh[tid + q * 256] = 0.f;
    float scale = ws[SC_OFF + g * 2], amin = ws[SC_OFF + g * 2 + 1];
    __syncthreads();

    int k = chunk * 256 + tid;
    int v = b * NN + k * CIN + c;
    float a = spikes[v] * scale;
    int bb = (int)((a - amin) * (4.0f * NB));
    bb = bb < 0 ? 0 : (bb > NB - 1 ? NB - 1 : bb);
    float sa, ca; __sincosf(a, &sa, &ca);
    float4 th = ((const float4*)theta)[v];
    float thv[4] = {th.x, th.y, th.z, th.w};
    #pragma unroll
    for (int d = 0; d < 4; ++d) {
        float sth, cth; __sincosf(thv[d], &sth, &cth);
        float sf = fmaf(cth, sa,  sth * ca);  // sin(th + a)
        float cf = fmaf(-sth, sa, cth * ca);  // cos(th + a)
        float sp = fmaf(-cth, sa, sth * ca);  // sin(th - a)
        float cq = fmaf(sth, sa,  cth * ca);  // cos(th - a)
        float* h = lh + (d * NB + bb) * HSTR;
        atomicAdd(h + 0, sf);      atomicAdd(h + 1, cf);
        atomicAdd(h + 2, a * sf);  atomicAdd(h + 3, a * cf);
        atomicAdd(h + 4, sp);      atomicAdd(h + 5, cq);
        atomicAdd(h + 6, a * sp);  atomicAdd(h + 7, a * cq);
    }
    __syncthreads();

    float* P = ws + P_OFF + (size_t)blk * PSZ;
    #pragma unroll
    for (int q = 0; q < 16; ++q) {
        int o = tid + q * 256;                // (d*NB+bb)*8 + ch
        P[o] = lh[(o >> 3) * HSTR + (o & 7)];
    }
}

// ---------- kernel 3: per (g,d): merge 16 partials once + scan -> H2 -------
__launch_bounds__(256)
__global__ void k_mscan(float* __restrict__ ws) {
    __shared__ float lh[NB * HSTR];           // 1152 floats
    int gd = blockIdx.x, g = gd >> 2, d = gd & 3;
    int tid = threadIdx.x, lane = tid & 63, w = tid >> 6;

    const float* Pg = ws + P_OFF + (size_t)(g * 16) * PSZ + d * NB * 8;
    #pragma unroll
    for (int q = 0; q < 4; ++q) {
        int o = tid + q * 256;                // < 1024 = NB*8
        float s = 0.f;
        #pragma unroll
        for (int p = 0; p < 16; ++p) s += Pg[(size_t)p * PSZ + o];
        lh[(o >> 3) * HSTR + (o & 7)] = s;
    }
    __syncthreads();

    // inclusive scan over 128 buckets; 4 waves x 2 channels, 2 buckets/lane
    #pragma unroll
    for (int p = 0; p < 2; ++p) {
        int ch = w * 2 + p;
        float x0 = lh[(lane * 2 + 0) * HSTR + ch];
        float x1 = lh[(lane * 2 + 1) * HSTR + ch];
        float i0 = x0, i1 = i0 + x1;
        float incl = i1;
        #pragma unroll
        for (int off = 1; off < 64; off <<= 1) {
            float o = __shfl_up(incl, off);
            if (lane >= off) incl += o;
        }
        float ebt = incl - i1;
        lh[(lane * 2 + 0) * HSTR + ch] = ebt + i0;
        lh[(lane * 2 + 1) * HSTR + ch] = ebt + i1;
    }
    __syncthreads();

    float* H2 = ws + H2_OFF + (size_t)gd * (NB * 8);
    #pragma unroll
    for (int q = 0; q < 4; ++q) {
        int o = tid + q * 256;
        H2[o] = lh[(o >> 3) * HSTR + (o & 7)];
    }
}

// ---------- kernel 4: per-node combine + gamma + normalize -----------------
__launch_bounds__(256)
__global__ void k_apply(const float* __restrict__ spikes,
                        const float* __restrict__ theta,
                        const float* __restrict__ gamma,
                        const float* __restrict__ ws,
                        float* __restrict__ out) {
    int blk = blockIdx.x, g = blk >> 4, chunk = blk & 15;
    int b = g / CIN, c = g % CIN;
    int tid = threadIdx.x;
    float scale = ws[SC_OFF + g * 2], amin = ws[SC_OFF + g * 2 + 1];
    int k = chunk * 256 + tid;
    int v = b * NN + k * CIN + c;
    float a = spikes[v] * scale;
    int bb = (int)((a - amin) * (4.0f * NB));
    bb = bb < 0 ? 0 : (bb > NB - 1 ? NB - 1 : bb);
    float sa, ca; __sincosf(a, &sa, &ca);
    float4 th = ((const float4*)theta)[v];
    float4 gm = ((const float4*)gamma)[v];
    float thv[4] = {th.x, th.y, th.z, th.w};
    float cp[4];
    #pragma unroll
    for (int d = 0; d < 4; ++d) {
        float sth, cth; __sincosf(thv[d], &sth, &cth);
        float sf = fmaf(cth, sa,  sth * ca);
        float cf = fmaf(-sth, sa, cth * ca);
        float sp = fmaf(-cth, sa, sth * ca);
        float cq = fmaf(sth, sa,  cth * ca);
        const float4* H4 = (const float4*)(ws + H2_OFF + (size_t)(g * 4 + d) * (NB * 8));
        float4 Plo = H4[bb * 2];
        float4 Phi = H4[bb * 2 + 1];
        float4 T   = H4[(NB - 1) * 2 + 1];
        float lowS = fmaf(0.25f - a, Plo.x, Plo.z);
        float lowC = fmaf(0.25f - a, Plo.y, Plo.w);
        float lower = cf * lowS - sf * lowC;
        float S4 = T.x - Phi.x, S5 = T.y - Phi.y;
        float S6 = T.z - Phi.z, S7 = T.w - Phi.w;
        float upS = fmaf(0.25f + a, S4, -S6);
        float upC = fmaf(0.25f + a, S5, -S7);
        float upper = cq * upS - sp * upC;
        cp[d] = (lower + upper) * (1.0f / (float)NC);
    }
    float tx = gm.x + cp[0], ty = gm.y + cp[1];
    float tz = gm.z + cp[2], tw = gm.w + cp[3];
    float nrm = sqrtf(tx * tx + ty * ty + tz * tz + tw * tw);
    float inv = 1.0f / fmaxf(nrm, 1e-6f);
    ((float4*)out)[v] = make_float4(tx * inv, ty * inv, tz * inv, tw * inv);
}

extern "C" void kernel_launch(void* const* d_in, const int* in_sizes, int n_in,
                              void* d_out, int out_size, void* d_ws, size_t ws_size,
                              hipStream_t stream) {
    const float* theta  = (const float*)d_in[0];
    const float* gamma  = (const float*)d_in[1];
    const float* spikes = (const float*)d_in[2];
    float* out = (float*)d_out;
    float* ws  = (float*)d_ws;

    hipLaunchKernelGGL(k_stats, dim3(NG),      dim3(256), 0, stream, spikes, ws);
    hipLaunchKernelGGL(k_hist,  dim3(NG * 16), dim3(256), 0, stream, spikes, theta, ws);
    hipLaunchKernelGGL(k_mscan, dim3(NG * 4),  dim3(256), 0, stream, ws);
    hipLaunchKernelGGL(k_apply, dim3(NG * 16), dim3(256), 0, stream,
                       spikes, theta, gamma, ws, out);
}